// Round 2
// baseline (297.469 us; speedup 1.0000x reference)
//
#include <hip/hip_runtime.h>
#include <cstddef>
#include <cstdint>

#define NPTS 8192
#define DIM  128

// MFMA path (round-13): single-plane f16 GEMM, K3=128, A staged ONCE.
// vs round-12: (1) the A-tile (128 rows x 128 K = 32KB) is kernel-invariant,
// so it is staged into a dedicated LDS region once at start instead of being
// re-staged every step (per-step global_load_lds 8 -> 4 per thread, barrier
// drain depth 16 -> 12, -2MB L2 read traffic per block); (2) zero-fill uses
// nontemporal stores so the 512KB/block dead-zero stream doesn't thrash the
// 4MB/XCD L2 that the B staging loads want to hit.
// LDS: A 2x16KB sections | B double-buffer 2x16KB = 64KB (merge dump reuses).
#define K3      128
#define BK      64
#define KITERS  (K3 / BK)        // 2
#define BM      128
#define BN      128
#define NSPLIT  8
#define CPB2    (NPTS / NSPLIT)  // 1024
#define NT2     (CPB2 / BN)      // 8

using f16x8 = __attribute__((ext_vector_type(8))) _Float16;
using f32x4 = __attribute__((ext_vector_type(4))) float;

// ws layout (bytes): H (f16 plane) | sq | part (8192 rows x 8 splits x 6 keys)
#define WS_HI   ((size_t)0)
#define WS_SQ   ((size_t)NPTS * DIM * 2)            // 2 MB
#define WS_PART (WS_SQ + (size_t)NPTS * 4)          // +32 KB
#define WS_NEED (WS_PART + (size_t)NPTS * 48 * 4)   // ~3.6 MB

// branchless sorted-ascending insert of packed key (positive floats only)
__device__ __forceinline__ void ins6(float t, float bd[6]) {
#pragma unroll
    for (int q = 0; q < 6; ++q) {
        float lo = fminf(bd[q], t);
        t        = fmaxf(bd[q], t);
        bd[q]    = lo;
    }
}

// classic (d2, idx) insert for the small final merge
__device__ __forceinline__ void insert6(float d, int idx, float bd[6], int bi[6]) {
    if (d < bd[5]) {
        bd[5] = d; bi[5] = idx;
#pragma unroll
        for (int q = 5; q >= 1; --q) {
            if (bd[q] < bd[q - 1]) {
                float td = bd[q]; bd[q] = bd[q - 1]; bd[q - 1] = td;
                int   ti = bi[q]; bi[q] = bi[q - 1]; bi[q - 1] = ti;
            }
        }
    }
}

__device__ __forceinline__ void async16(const void* g, void* l) {
    __builtin_amdgcn_global_load_lds(
        (const __attribute__((address_space(1))) void*)g,
        (__attribute__((address_space(3))) void*)l,
        16, 0, 0);
}

// K0: fp32 -> f16 plane (RNE via v_cvt_f16_f32) + per-row |f16|^2 via shfl.
// 2 elems/thread: one wave == one 128-dim row, so no LDS reduction needed.
__global__ __launch_bounds__(256) void prep3(const float* __restrict__ F,
                                             short* __restrict__ H,
                                             float* __restrict__ sq) {
    const int tid = threadIdx.x;
    const int idx = blockIdx.x * 512 + tid * 2;
    float2 f = *(const float2*)&F[idx];
    _Float16 h0 = (_Float16)f.x;          // RNE
    _Float16 h1 = (_Float16)f.y;
    ushort2 hp;
    hp.x = __builtin_bit_cast(unsigned short, h0);
    hp.y = __builtin_bit_cast(unsigned short, h1);
    *(ushort2*)&H[idx] = hp;
    const float a = (float)h0, b = (float)h1;
    float s = a * a + b * b;              // sq of the QUANTIZED point
#pragma unroll
    for (int m = 32; m >= 1; m >>= 1) s += __shfl_xor(s, m, 64);
    if ((tid & 63) == 0) sq[blockIdx.x * 4 + (tid >> 6)] = s;
}

// K1: swapped-operand f16 MFMA distance + packed-key top-6 + interleaved
// nontemporal zero-fill of the output strip. A staged once; B double-buffered.
__global__ __launch_bounds__(256, 2) void knn_mfma3(const short* __restrict__ H,
                                                    const float* __restrict__ sq,
                                                    float* __restrict__ part,
                                                    float* __restrict__ out) {
    __shared__ __align__(16) char smraw[65536];   // [A 32KB][B dbuf 2x16KB]; dump reuses 24KB
    char* const smA = smraw;
    char* const smB = smraw + 32768;

    const int tid  = threadIdx.x;
    const int lane = tid & 63;
    const int w    = tid >> 6;        // wave 0..3
    const int wy   = w >> 1;          // col half
    const int wx   = w & 1;           // row half
    const int q    = lane >> 4;       // quad 0..3
    const int pl   = lane & 15;

    const int bx   = blockIdx.x;
    const int rb   = bx & 63;
    const int cs   = bx >> 6;
    const int row0 = rb * BM;
    const int col0 = cs * CPB2;

    // B staging decode: slot = w*256 + i*64 + lane -> (point, logical chunk)
    int pS[4], cS[4];
#pragma unroll
    for (int i = 0; i < 4; ++i) {
        int ch = w * 256 + i * 64 + lane;
        pS[i] = ch >> 3;
        cS[i] = (ch & 7) ^ (pS[i] & 7);
    }

    // frag LDS byte offsets: phys chunk = point*8 + (kchunk ^ (point&7))
    int colOff[4][2], rowOff[4][2];
#pragma unroll
    for (int f = 0; f < 4; ++f) {
#pragma unroll
        for (int s = 0; s < 2; ++s) {
            int pc = wy * 64 + f * 16 + pl;
            int cc = (s * 4 + q) ^ (pc & 7);
            colOff[f][s] = (pc * 64 + cc * 8) * 2;
            int pr = wx * 64 + f * 16 + pl;
            int cr = (s * 4 + q) ^ (pr & 7);
            rowOff[f][s] = (pr * 64 + cr * 8) * 2;
        }
    }

    float sqr4[4];
#pragma unroll
    for (int fj = 0; fj < 4; ++fj) sqr4[fj] = sq[row0 + wx * 64 + fj * 16 + pl];

    // packed-key top-6 per owned row (4 rows per thread)
    float bd[4][6];
#pragma unroll
    for (int fj = 0; fj < 4; ++fj)
#pragma unroll
        for (int k = 0; k < 6; ++k) bd[fj][k] = 3.0e38f;

    // ---- stage A once: 2048 chunks (2 K-sections x 128 rows x 8 chunks).
    // dest slot = i*256 + tid (wave-uniform base + lane*16); source address
    // carries the swizzle: slot -> (s16, p, phys), logical chunk = phys^(p&7).
#pragma unroll
    for (int i = 0; i < 8; ++i) {
        int slot = i * 256 + tid;
        int s16  = slot >> 10;
        int wi   = slot & 1023;
        int p    = wi >> 3;
        int phys = wi & 7;
        int c8   = phys ^ (p & 7);
        const short* gA = H + (size_t)(row0 + p) * DIM + s16 * 64 + c8 * 8;
        async16(gA, smA + slot * 16);
    }

    auto stageB = [&](int b, int nt, int nk) {
        const int half = nk * 64;                  // K-section within the row
        const int tcn  = col0 + nt * BN;
        char* baseB = smB + b * 16384;
#pragma unroll
        for (int i = 0; i < 4; ++i) {
            const short* gB = H + (size_t)(tcn + pS[i]) * DIM + half + cS[i] * 8;
            async16(gB, baseB + (w * 256 + i * 64) * 16);
        }
    };

    stageB(0, 0, 0);
    int sidx = 0;

    const f32x4 z4 = {0.f, 0.f, 0.f, 0.f};

    for (int tile = 0; tile < NT2; ++tile) {
        const int tc0 = col0 + tile * BN;

        f32x4 acc[4][4];
#pragma unroll
        for (int fi = 0; fi < 4; ++fi)
#pragma unroll
            for (int fj = 0; fj < 4; ++fj) acc[fi][fj] = 0.0f;

        for (int kk = 0; kk < KITERS; ++kk) {
            const int b = sidx & 1;
            __syncthreads();
            int nk = kk + 1, nt = tile;
            if (nk == KITERS) { nk = 0; nt = tile + 1; }
            if (nt < NT2) stageB(b ^ 1, nt, nk);

            // interleaved zero-fill quota: 8 f32x4/thread/step, nontemporal
            // (no L2 allocate -> the dead-zero stream doesn't evict the H
            // plane the staging loads hit). 16 steps x 2048 f32x4 = full
            // 128x1024 region.
            {
                int base = sidx * 2048 + tid;
#pragma unroll
                for (int it = 0; it < 8; ++it) {
                    int flat = base + it * 256;
                    int r  = flat >> 8;           // 0..127
                    int c4 = (flat & 255) * 4;    // 0..1020
                    __builtin_nontemporal_store(
                        z4, (f32x4*)&out[(size_t)(row0 + r) * NPTS + col0 + c4]);
                }
            }

            char* baseB = smB + b * 16384;
            const char* baseA = smA + (kk << 14);  // K-section kk
#pragma unroll
            for (int s = 0; s < 2; ++s) {
                f16x8 cf[4], rf[4];
#pragma unroll
                for (int fi = 0; fi < 4; ++fi)
                    cf[fi] = *(const f16x8*)(baseB + colOff[fi][s]);
#pragma unroll
                for (int fj = 0; fj < 4; ++fj)
                    rf[fj] = *(const f16x8*)(baseA + rowOff[fj][s]);
#pragma unroll
                for (int fi = 0; fi < 4; ++fi)
#pragma unroll
                    for (int fj = 0; fj < 4; ++fj)
                        acc[fi][fj] = __builtin_amdgcn_mfma_f32_16x16x32_f16(
                            cf[fi], rf[fj], acc[fi][fj], 0, 0, 0);
            }
            ++sidx;
        }

        // in-register epilogue: rows r = wx*64+fj*16+pl, cols c = wy*64+fi*16+q*4+reg
        const bool diag = (tc0 == row0);
        float4 sqc4[4];
#pragma unroll
        for (int fi = 0; fi < 4; ++fi)
            sqc4[fi] = *(const float4*)&sq[tc0 + wy * 64 + fi * 16 + q * 4];

#pragma unroll
        for (int fj = 0; fj < 4; ++fj) {
            const float sr = sqr4[fj];
            const int   r  = wx * 64 + fj * 16 + pl;
#pragma unroll
            for (int fi = 0; fi < 4; ++fi) {
                const float* sc = (const float*)&sqc4[fi];
#pragma unroll
                for (int reg = 0; reg < 4; ++reg) {
                    const int c = wy * 64 + fi * 16 + q * 4 + reg;
                    float d2 = fmaf(-2.0f, acc[fi][fj][reg], sr + sc[reg]);
                    d2 = fmaxf(d2, 1e-30f);
                    if (diag && r == c) d2 = 1e-30f;    // self-distance
                    uint32_t kb = (__float_as_uint(d2) & 0xFFFFFC00u)
                                  | (uint32_t)(tile * BN + c);   // 10-bit local col
                    ins6(__uint_as_float(kb), bd[fj]);
                }
            }
        }
    }

    // block merge: 8 lists per row (wy x q) -> 6 packed keys per row per split
    __syncthreads();                       // all frag reads done; reuse smraw
    float* dump = (float*)smraw;           // 128 rows * 8 copies * 6 = 24 KB
#pragma unroll
    for (int fj = 0; fj < 4; ++fj) {
        const int r    = wx * 64 + fj * 16 + pl;
        const int copy = wy * 4 + q;
        float* d = &dump[(size_t)(r * 8 + copy) * 6];
#pragma unroll
        for (int k = 0; k < 6; ++k) d[k] = bd[fj][k];
    }
    __syncthreads();
    if (tid < 128) {
        float md[6];
#pragma unroll
        for (int k = 0; k < 6; ++k) md[k] = 3.0e38f;
        const float* src = &dump[(size_t)tid * 48];
#pragma unroll
        for (int g = 0; g < 48; ++g) ins6(src[g], md);
        float* dst = part + (size_t)(row0 + tid) * 48 + cs * 6;
#pragma unroll
        for (int k = 0; k < 6; ++k) dst[k] = md[k];
    }
}

// K2: merge 8 packed-key lists per row (direct global reads, no LDS),
// compute weights, scatter 6 values.
__global__ __launch_bounds__(256) void final3(const float* __restrict__ part,
                                              float* __restrict__ out) {
    const int r = blockIdx.x * 256 + threadIdx.x;
    const float4* p4 = (const float4*)(part + (size_t)r * 48);
    float4 buf[12];
#pragma unroll
    for (int i = 0; i < 12; ++i) buf[i] = p4[i];
    const float* keys = (const float*)buf;

    float md[6]; int mi[6];
#pragma unroll
    for (int k = 0; k < 6; ++k) { md[k] = 3.0e38f; mi[k] = 0; }
#pragma unroll
    for (int s = 0; s < 8; ++s)
#pragma unroll
        for (int k = 0; k < 6; ++k) {
            uint32_t kb = __float_as_uint(keys[s * 6 + k]);
            float d2 = __uint_as_float(kb & 0xFFFFFC00u);
            int  col = s * CPB2 + (int)(kb & 1023u);
            insert6(d2, col, md, mi);
        }
    const float T = sqrtf(md[5]);
    float wv[6], norm = 0.f;
#pragma unroll
    for (int k = 0; k < 6; ++k) { wv[k] = T - sqrtf(md[k]) + 1e-10f; norm += wv[k]; }
    const float inv = 1.0f / fmaxf(norm, 1e-12f);
    const size_t base = (size_t)r * NPTS;
#pragma unroll
    for (int k = 0; k < 6; ++k) out[base + mi[k]] = wv[k] * inv;
}

// ------------------- fallback fp32 path (round 1, passing) -------------------
#define RB      32
#define CT      64
#define SPLITS  8
#define CPB     (NPTS / SPLITS)
#define NTILES  (CPB / CT)
#define PADS    132

__global__ __launch_bounds__(256) void knn_partial(const float* __restrict__ F,
                                                   float* __restrict__ out) {
    __shared__ float rowF[RB * PADS];
    __shared__ float colF[CT * PADS];
    __shared__ float sqr[RB];
    __shared__ float sqc[CT];

    const int tid  = threadIdx.x;
    const int bx   = blockIdx.x;
    const int rb   = bx & ((NPTS / RB) - 1);
    const int cs   = bx >> 8;
    const int row0 = rb * RB;
    const int col0 = cs * CPB;

#pragma unroll
    for (int m = 0; m < 4; ++m) {
        int flat = m * 256 + tid;
        int r = flat >> 5, kq = flat & 31;
        float4 v = *(const float4*)&F[(size_t)(row0 + r) * DIM + kq * 4];
        *(float4*)&rowF[r * PADS + kq * 4] = v;
    }
    __syncthreads();
    if (tid < RB) {
        float s = 0.f;
#pragma unroll
        for (int kq = 0; kq < 32; ++kq) {
            float4 v = *(const float4*)&rowF[tid * PADS + kq * 4];
            s += v.x * v.x + v.y * v.y + v.z * v.z + v.w * v.w;
        }
        sqr[tid] = s;
    }

    const int rl = tid >> 4;
    const int cl = tid & 15;

    float bd[2][6];
    int   bi[2][6];
#pragma unroll
    for (int i = 0; i < 2; ++i)
#pragma unroll
        for (int k = 0; k < 6; ++k) { bd[i][k] = 3.0e38f; bi[i][k] = 0; }

    for (int t = 0; t < NTILES; ++t) {
        const int cbase = col0 + t * CT;
        __syncthreads();
#pragma unroll
        for (int m = 0; m < 8; ++m) {
            int flat = m * 256 + tid;
            int c = flat >> 5, kq = flat & 31;
            float4 v = *(const float4*)&F[(size_t)(cbase + c) * DIM + kq * 4];
            *(float4*)&colF[c * PADS + kq * 4] = v;
        }
        __syncthreads();
        if (tid < CT) {
            float s = 0.f;
#pragma unroll
            for (int kq = 0; kq < 32; ++kq) {
                float4 v = *(const float4*)&colF[tid * PADS + kq * 4];
                s += v.x * v.x + v.y * v.y + v.z * v.z + v.w * v.w;
            }
            sqc[tid] = s;
        }
        __syncthreads();

        float acc[2][4];
#pragma unroll
        for (int i = 0; i < 2; ++i)
#pragma unroll
            for (int j = 0; j < 4; ++j) acc[i][j] = 0.f;

#pragma unroll 4
        for (int kq = 0; kq < 32; ++kq) {
            float4 a[2], b[4];
#pragma unroll
            for (int i = 0; i < 2; ++i)
                a[i] = *(const float4*)&rowF[(rl + 16 * i) * PADS + kq * 4];
#pragma unroll
            for (int j = 0; j < 4; ++j)
                b[j] = *(const float4*)&colF[(cl + 16 * j) * PADS + kq * 4];
#pragma unroll
            for (int i = 0; i < 2; ++i)
#pragma unroll
                for (int j = 0; j < 4; ++j) {
                    acc[i][j] = fmaf(a[i].x, b[j].x, acc[i][j]);
                    acc[i][j] = fmaf(a[i].y, b[j].y, acc[i][j]);
                    acc[i][j] = fmaf(a[i].z, b[j].z, acc[i][j]);
                    acc[i][j] = fmaf(a[i].w, b[j].w, acc[i][j]);
                }
        }

#pragma unroll
        for (int i = 0; i < 2; ++i) {
            const int r = rl + 16 * i;
            const int gr = row0 + r;
#pragma unroll
            for (int j = 0; j < 4; ++j) {
                const int c = cl + 16 * j;
                const int gc = cbase + c;
                float d2 = sqr[r] + sqc[c] - 2.0f * acc[i][j];
                d2 = (gr == gc) ? 1e-30f : fmaxf(d2, 1e-30f);
                insert6(d2, gc, bd[i], bi[i]);
            }
        }
    }

    __syncthreads();
    float* cd = colF;
    float* ci = rowF;
#pragma unroll
    for (int i = 0; i < 2; ++i) {
        const int r = rl + 16 * i;
#pragma unroll
        for (int k = 0; k < 6; ++k) {
            cd[(r * 16 + cl) * 6 + k] = bd[i][k];
            ci[(r * 16 + cl) * 6 + k] = __int_as_float(bi[i][k]);
        }
    }
    __syncthreads();
    if (tid < RB) {
        float md[6]; int mi[6];
#pragma unroll
        for (int k = 0; k < 6; ++k) { md[k] = 3.0e38f; mi[k] = 0; }
        for (int g = 0; g < 16; ++g) {
#pragma unroll
            for (int k = 0; k < 6; ++k)
                insert6(cd[(tid * 16 + g) * 6 + k],
                        __float_as_int(ci[(tid * 16 + g) * 6 + k]), md, mi);
        }
        float* dst = &out[(size_t)(row0 + tid) * NPTS + cs * 12];
#pragma unroll
        for (int k = 0; k < 6; ++k) {
            dst[k] = md[k];
            dst[6 + k] = __int_as_float(mi[k]);
        }
    }
}

__global__ __launch_bounds__(256) void knn_finalize(float* __restrict__ out) {
    __shared__ float pbuf[SPLITS * 12];
    __shared__ float w_s[6];
    __shared__ int   wi_s[6];

    const int    tid  = threadIdx.x;
    const size_t base = (size_t)blockIdx.x * NPTS;

    if (tid < SPLITS * 12) pbuf[tid] = out[base + tid];
    __syncthreads();

    if (tid == 0) {
        float md[6]; int mi[6];
#pragma unroll
        for (int k = 0; k < 6; ++k) { md[k] = 3.0e38f; mi[k] = 0; }
        for (int s = 0; s < SPLITS; ++s)
#pragma unroll
            for (int k = 0; k < 6; ++k)
                insert6(pbuf[s * 12 + k], __float_as_int(pbuf[s * 12 + 6 + k]), md, mi);
        const float T = sqrtf(md[5]);
        float w[6]; float norm = 0.f;
#pragma unroll
        for (int k = 0; k < 6; ++k) { w[k] = T - sqrtf(md[k]) + 1e-10f; norm += w[k]; }
        const float inv = 1.0f / fmaxf(norm, 1e-12f);
#pragma unroll
        for (int k = 0; k < 6; ++k) { w_s[k] = w[k] * inv; wi_s[k] = mi[k]; }
    }
    __syncthreads();

#pragma unroll
    for (int m = 0; m < 8; ++m)
        *(float4*)&out[base + (size_t)(m * 256 + tid) * 4] = make_float4(0.f, 0.f, 0.f, 0.f);
    __syncthreads();

    if (tid < 6) out[base + wi_s[tid]] = w_s[tid];
}

extern "C" void kernel_launch(void* const* d_in, const int* in_sizes, int n_in,
                              void* d_out, int out_size, void* d_ws, size_t ws_size,
                              hipStream_t stream) {
    const float* F   = (const float*)d_in[0];
    float*       out = (float*)d_out;
    if (ws_size >= WS_NEED) {
        short* H   = (short*)((char*)d_ws + WS_HI);
        float* sqp = (float*)((char*)d_ws + WS_SQ);
        float* prt = (float*)((char*)d_ws + WS_PART);
        prep3<<<dim3(NPTS * DIM / 512), dim3(256), 0, stream>>>(F, H, sqp);
        knn_mfma3<<<dim3(64 * NSPLIT), dim3(256), 0, stream>>>(H, sqp, prt, out);
        final3<<<dim3(NPTS / 256), dim3(256), 0, stream>>>(prt, out);
    } else {
        knn_partial<<<dim3((NPTS / RB) * SPLITS), dim3(256), 0, stream>>>(F, out);
        knn_finalize<<<dim3(NPTS), dim3(256), 0, stream>>>(out);
    }
}

// Round 3
// 280.658 us; speedup vs baseline: 1.0599x; 1.0599x over previous
//
#include <hip/hip_runtime.h>
#include <cstddef>
#include <cstdint>

#define NPTS 8192
#define DIM  128

// MFMA path (round-14): single-plane f16 GEMM, K3=128, A staged ONCE,
// zero-fill via REGULAR stores.
// Post-mortem of r13: nontemporal zero-fill stores ack from HBM (~900cy)
// instead of L2 (~200cy) and every barrier-step drains vmcnt(0) over them
// -> per-step stall that cancelled the A-once gain. The L2-thrash premise
// was also wrong: the H plane is 2MB and stays L2-resident per-XCD anyway.
// So: keep A-once (fewer load issues, shallower drains), revert to regular
// stores (L2 write-allocate acks cheaply at the next barrier).
// LDS: A 2x16KB K-sections | B double-buffer 2x16KB = 64KB (merge dump reuses).
#define K3      128
#define BK      64
#define KITERS  (K3 / BK)        // 2
#define BM      128
#define BN      128
#define NSPLIT  8
#define CPB2    (NPTS / NSPLIT)  // 1024
#define NT2     (CPB2 / BN)      // 8

using f16x8 = __attribute__((ext_vector_type(8))) _Float16;
using f32x4 = __attribute__((ext_vector_type(4))) float;

// ws layout (bytes): H (f16 plane) | sq | part (8192 rows x 8 splits x 6 keys)
#define WS_HI   ((size_t)0)
#define WS_SQ   ((size_t)NPTS * DIM * 2)            // 2 MB
#define WS_PART (WS_SQ + (size_t)NPTS * 4)          // +32 KB
#define WS_NEED (WS_PART + (size_t)NPTS * 48 * 4)   // ~3.6 MB

// branchless sorted-ascending insert of packed key (positive floats only)
__device__ __forceinline__ void ins6(float t, float bd[6]) {
#pragma unroll
    for (int q = 0; q < 6; ++q) {
        float lo = fminf(bd[q], t);
        t        = fmaxf(bd[q], t);
        bd[q]    = lo;
    }
}

// classic (d2, idx) insert for the small final merge
__device__ __forceinline__ void insert6(float d, int idx, float bd[6], int bi[6]) {
    if (d < bd[5]) {
        bd[5] = d; bi[5] = idx;
#pragma unroll
        for (int q = 5; q >= 1; --q) {
            if (bd[q] < bd[q - 1]) {
                float td = bd[q]; bd[q] = bd[q - 1]; bd[q - 1] = td;
                int   ti = bi[q]; bi[q] = bi[q - 1]; bi[q - 1] = ti;
            }
        }
    }
}

__device__ __forceinline__ void async16(const void* g, void* l) {
    __builtin_amdgcn_global_load_lds(
        (const __attribute__((address_space(1))) void*)g,
        (__attribute__((address_space(3))) void*)l,
        16, 0, 0);
}

// K0: fp32 -> f16 plane (RNE via v_cvt_f16_f32) + per-row |f16|^2 via shfl.
// 2 elems/thread: one wave == one 128-dim row, so no LDS reduction needed.
__global__ __launch_bounds__(256) void prep3(const float* __restrict__ F,
                                             short* __restrict__ H,
                                             float* __restrict__ sq) {
    const int tid = threadIdx.x;
    const int idx = blockIdx.x * 512 + tid * 2;
    float2 f = *(const float2*)&F[idx];
    _Float16 h0 = (_Float16)f.x;          // RNE
    _Float16 h1 = (_Float16)f.y;
    ushort2 hp;
    hp.x = __builtin_bit_cast(unsigned short, h0);
    hp.y = __builtin_bit_cast(unsigned short, h1);
    *(ushort2*)&H[idx] = hp;
    const float a = (float)h0, b = (float)h1;
    float s = a * a + b * b;              // sq of the QUANTIZED point
#pragma unroll
    for (int m = 32; m >= 1; m >>= 1) s += __shfl_xor(s, m, 64);
    if ((tid & 63) == 0) sq[blockIdx.x * 4 + (tid >> 6)] = s;
}

// K1: swapped-operand f16 MFMA distance + packed-key top-6 + interleaved
// zero-fill of the output strip. A staged once; B double-buffered.
__global__ __launch_bounds__(256, 2) void knn_mfma3(const short* __restrict__ H,
                                                    const float* __restrict__ sq,
                                                    float* __restrict__ part,
                                                    float* __restrict__ out) {
    __shared__ __align__(16) char smraw[65536];   // [A 32KB][B dbuf 2x16KB]; dump reuses 24KB
    char* const smA = smraw;
    char* const smB = smraw + 32768;

    const int tid  = threadIdx.x;
    const int lane = tid & 63;
    const int w    = tid >> 6;        // wave 0..3
    const int wy   = w >> 1;          // col half
    const int wx   = w & 1;           // row half
    const int q    = lane >> 4;       // quad 0..3
    const int pl   = lane & 15;

    const int bx   = blockIdx.x;
    const int rb   = bx & 63;
    const int cs   = bx >> 6;
    const int row0 = rb * BM;
    const int col0 = cs * CPB2;

    // B staging decode: slot = w*256 + i*64 + lane -> (point, logical chunk)
    int pS[4], cS[4];
#pragma unroll
    for (int i = 0; i < 4; ++i) {
        int ch = w * 256 + i * 64 + lane;
        pS[i] = ch >> 3;
        cS[i] = (ch & 7) ^ (pS[i] & 7);
    }

    // frag LDS byte offsets: phys chunk = point*8 + (kchunk ^ (point&7))
    int colOff[4][2], rowOff[4][2];
#pragma unroll
    for (int f = 0; f < 4; ++f) {
#pragma unroll
        for (int s = 0; s < 2; ++s) {
            int pc = wy * 64 + f * 16 + pl;
            int cc = (s * 4 + q) ^ (pc & 7);
            colOff[f][s] = (pc * 64 + cc * 8) * 2;
            int pr = wx * 64 + f * 16 + pl;
            int cr = (s * 4 + q) ^ (pr & 7);
            rowOff[f][s] = (pr * 64 + cr * 8) * 2;
        }
    }

    float sqr4[4];
#pragma unroll
    for (int fj = 0; fj < 4; ++fj) sqr4[fj] = sq[row0 + wx * 64 + fj * 16 + pl];

    // packed-key top-6 per owned row (4 rows per thread)
    float bd[4][6];
#pragma unroll
    for (int fj = 0; fj < 4; ++fj)
#pragma unroll
        for (int k = 0; k < 6; ++k) bd[fj][k] = 3.0e38f;

    // ---- stage A once: 2048 chunks (2 K-sections x 128 rows x 8 chunks).
    // dest slot = i*256 + tid (wave-uniform base + lane*16); source address
    // carries the swizzle: slot -> (s16, p, phys), logical chunk = phys^(p&7).
#pragma unroll
    for (int i = 0; i < 8; ++i) {
        int slot = i * 256 + tid;
        int s16  = slot >> 10;
        int wi   = slot & 1023;
        int p    = wi >> 3;
        int phys = wi & 7;
        int c8   = phys ^ (p & 7);
        const short* gA = H + (size_t)(row0 + p) * DIM + s16 * 64 + c8 * 8;
        async16(gA, smA + slot * 16);
    }

    auto stageB = [&](int b, int nt, int nk) {
        const int half = nk * 64;                  // K-section within the row
        const int tcn  = col0 + nt * BN;
        char* baseB = smB + b * 16384;
#pragma unroll
        for (int i = 0; i < 4; ++i) {
            const short* gB = H + (size_t)(tcn + pS[i]) * DIM + half + cS[i] * 8;
            async16(gB, baseB + (w * 256 + i * 64) * 16);
        }
    };

    stageB(0, 0, 0);
    int sidx = 0;

    const f32x4 z4 = {0.f, 0.f, 0.f, 0.f};

    for (int tile = 0; tile < NT2; ++tile) {
        const int tc0 = col0 + tile * BN;

        f32x4 acc[4][4];
#pragma unroll
        for (int fi = 0; fi < 4; ++fi)
#pragma unroll
            for (int fj = 0; fj < 4; ++fj) acc[fi][fj] = 0.0f;

        for (int kk = 0; kk < KITERS; ++kk) {
            const int b = sidx & 1;
            __syncthreads();
            int nk = kk + 1, nt = tile;
            if (nk == KITERS) { nk = 0; nt = tile + 1; }
            if (nt < NT2) stageB(b ^ 1, nt, nk);

            // interleaved zero-fill quota: 8 f32x4/thread/step (regular stores:
            // L2 ack drains cheaply at the next barrier; writeback is async).
            // 16 steps x 2048 f32x4 = 32768 = the full 128x1024 region.
            {
                int base = sidx * 2048 + tid;
#pragma unroll
                for (int it = 0; it < 8; ++it) {
                    int flat = base + it * 256;
                    int r  = flat >> 8;           // 0..127
                    int c4 = (flat & 255) * 4;    // 0..1020
                    *(f32x4*)&out[(size_t)(row0 + r) * NPTS + col0 + c4] = z4;
                }
            }

            char* baseB = smB + b * 16384;
            const char* baseA = smA + (kk << 14);  // K-section kk
#pragma unroll
            for (int s = 0; s < 2; ++s) {
                f16x8 cf[4], rf[4];
#pragma unroll
                for (int fi = 0; fi < 4; ++fi)
                    cf[fi] = *(const f16x8*)(baseB + colOff[fi][s]);
#pragma unroll
                for (int fj = 0; fj < 4; ++fj)
                    rf[fj] = *(const f16x8*)(baseA + rowOff[fj][s]);
#pragma unroll
                for (int fi = 0; fi < 4; ++fi)
#pragma unroll
                    for (int fj = 0; fj < 4; ++fj)
                        acc[fi][fj] = __builtin_amdgcn_mfma_f32_16x16x32_f16(
                            cf[fi], rf[fj], acc[fi][fj], 0, 0, 0);
            }
            ++sidx;
        }

        // in-register epilogue: rows r = wx*64+fj*16+pl, cols c = wy*64+fi*16+q*4+reg
        const bool diag = (tc0 == row0);
        float4 sqc4[4];
#pragma unroll
        for (int fi = 0; fi < 4; ++fi)
            sqc4[fi] = *(const float4*)&sq[tc0 + wy * 64 + fi * 16 + q * 4];

#pragma unroll
        for (int fj = 0; fj < 4; ++fj) {
            const float sr = sqr4[fj];
            const int   r  = wx * 64 + fj * 16 + pl;
#pragma unroll
            for (int fi = 0; fi < 4; ++fi) {
                const float* sc = (const float*)&sqc4[fi];
#pragma unroll
                for (int reg = 0; reg < 4; ++reg) {
                    const int c = wy * 64 + fi * 16 + q * 4 + reg;
                    float d2 = fmaf(-2.0f, acc[fi][fj][reg], sr + sc[reg]);
                    d2 = fmaxf(d2, 1e-30f);
                    if (diag && r == c) d2 = 1e-30f;    // self-distance
                    uint32_t kb = (__float_as_uint(d2) & 0xFFFFFC00u)
                                  | (uint32_t)(tile * BN + c);   // 10-bit local col
                    ins6(__uint_as_float(kb), bd[fj]);
                }
            }
        }
    }

    // block merge: 8 lists per row (wy x q) -> 6 packed keys per row per split
    __syncthreads();                       // all frag reads done; reuse smraw
    float* dump = (float*)smraw;           // 128 rows * 8 copies * 6 = 24 KB
#pragma unroll
    for (int fj = 0; fj < 4; ++fj) {
        const int r    = wx * 64 + fj * 16 + pl;
        const int copy = wy * 4 + q;
        float* d = &dump[(size_t)(r * 8 + copy) * 6];
#pragma unroll
        for (int k = 0; k < 6; ++k) d[k] = bd[fj][k];
    }
    __syncthreads();
    if (tid < 128) {
        float md[6];
#pragma unroll
        for (int k = 0; k < 6; ++k) md[k] = 3.0e38f;
        const float* src = &dump[(size_t)tid * 48];
#pragma unroll
        for (int g = 0; g < 48; ++g) ins6(src[g], md);
        float* dst = part + (size_t)(row0 + tid) * 48 + cs * 6;
#pragma unroll
        for (int k = 0; k < 6; ++k) dst[k] = md[k];
    }
}

// K2: merge 8 packed-key lists per row (direct global reads, no LDS),
// compute weights, scatter 6 values.
__global__ __launch_bounds__(256) void final3(const float* __restrict__ part,
                                              float* __restrict__ out) {
    const int r = blockIdx.x * 256 + threadIdx.x;
    const float4* p4 = (const float4*)(part + (size_t)r * 48);
    float4 buf[12];
#pragma unroll
    for (int i = 0; i < 12; ++i) buf[i] = p4[i];
    const float* keys = (const float*)buf;

    float md[6]; int mi[6];
#pragma unroll
    for (int k = 0; k < 6; ++k) { md[k] = 3.0e38f; mi[k] = 0; }
#pragma unroll
    for (int s = 0; s < 8; ++s)
#pragma unroll
        for (int k = 0; k < 6; ++k) {
            uint32_t kb = __float_as_uint(keys[s * 6 + k]);
            float d2 = __uint_as_float(kb & 0xFFFFFC00u);
            int  col = s * CPB2 + (int)(kb & 1023u);
            insert6(d2, col, md, mi);
        }
    const float T = sqrtf(md[5]);
    float wv[6], norm = 0.f;
#pragma unroll
    for (int k = 0; k < 6; ++k) { wv[k] = T - sqrtf(md[k]) + 1e-10f; norm += wv[k]; }
    const float inv = 1.0f / fmaxf(norm, 1e-12f);
    const size_t base = (size_t)r * NPTS;
#pragma unroll
    for (int k = 0; k < 6; ++k) out[base + mi[k]] = wv[k] * inv;
}

// ------------------- fallback fp32 path (round 1, passing) -------------------
#define RB      32
#define CT      64
#define SPLITS  8
#define CPB     (NPTS / SPLITS)
#define NTILES  (CPB / CT)
#define PADS    132

__global__ __launch_bounds__(256) void knn_partial(const float* __restrict__ F,
                                                   float* __restrict__ out) {
    __shared__ float rowF[RB * PADS];
    __shared__ float colF[CT * PADS];
    __shared__ float sqr[RB];
    __shared__ float sqc[CT];

    const int tid  = threadIdx.x;
    const int bx   = blockIdx.x;
    const int rb   = bx & ((NPTS / RB) - 1);
    const int cs   = bx >> 8;
    const int row0 = rb * RB;
    const int col0 = cs * CPB;

#pragma unroll
    for (int m = 0; m < 4; ++m) {
        int flat = m * 256 + tid;
        int r = flat >> 5, kq = flat & 31;
        float4 v = *(const float4*)&F[(size_t)(row0 + r) * DIM + kq * 4];
        *(float4*)&rowF[r * PADS + kq * 4] = v;
    }
    __syncthreads();
    if (tid < RB) {
        float s = 0.f;
#pragma unroll
        for (int kq = 0; kq < 32; ++kq) {
            float4 v = *(const float4*)&rowF[tid * PADS + kq * 4];
            s += v.x * v.x + v.y * v.y + v.z * v.z + v.w * v.w;
        }
        sqr[tid] = s;
    }

    const int rl = tid >> 4;
    const int cl = tid & 15;

    float bd[2][6];
    int   bi[2][6];
#pragma unroll
    for (int i = 0; i < 2; ++i)
#pragma unroll
        for (int k = 0; k < 6; ++k) { bd[i][k] = 3.0e38f; bi[i][k] = 0; }

    for (int t = 0; t < NTILES; ++t) {
        const int cbase = col0 + t * CT;
        __syncthreads();
#pragma unroll
        for (int m = 0; m < 8; ++m) {
            int flat = m * 256 + tid;
            int c = flat >> 5, kq = flat & 31;
            float4 v = *(const float4*)&F[(size_t)(cbase + c) * DIM + kq * 4];
            *(float4*)&colF[c * PADS + kq * 4] = v;
        }
        __syncthreads();
        if (tid < CT) {
            float s = 0.f;
#pragma unroll
            for (int kq = 0; kq < 32; ++kq) {
                float4 v = *(const float4*)&colF[tid * PADS + kq * 4];
                s += v.x * v.x + v.y * v.y + v.z * v.z + v.w * v.w;
            }
            sqc[tid] = s;
        }
        __syncthreads();

        float acc[2][4];
#pragma unroll
        for (int i = 0; i < 2; ++i)
#pragma unroll
            for (int j = 0; j < 4; ++j) acc[i][j] = 0.f;

#pragma unroll 4
        for (int kq = 0; kq < 32; ++kq) {
            float4 a[2], b[4];
#pragma unroll
            for (int i = 0; i < 2; ++i)
                a[i] = *(const float4*)&rowF[(rl + 16 * i) * PADS + kq * 4];
#pragma unroll
            for (int j = 0; j < 4; ++j)
                b[j] = *(const float4*)&colF[(cl + 16 * j) * PADS + kq * 4];
#pragma unroll
            for (int i = 0; i < 2; ++i)
#pragma unroll
                for (int j = 0; j < 4; ++j) {
                    acc[i][j] = fmaf(a[i].x, b[j].x, acc[i][j]);
                    acc[i][j] = fmaf(a[i].y, b[j].y, acc[i][j]);
                    acc[i][j] = fmaf(a[i].z, b[j].z, acc[i][j]);
                    acc[i][j] = fmaf(a[i].w, b[j].w, acc[i][j]);
                }
        }

#pragma unroll
        for (int i = 0; i < 2; ++i) {
            const int r = rl + 16 * i;
            const int gr = row0 + r;
#pragma unroll
            for (int j = 0; j < 4; ++j) {
                const int c = cl + 16 * j;
                const int gc = cbase + c;
                float d2 = sqr[r] + sqc[c] - 2.0f * acc[i][j];
                d2 = (gr == gc) ? 1e-30f : fmaxf(d2, 1e-30f);
                insert6(d2, gc, bd[i], bi[i]);
            }
        }
    }

    __syncthreads();
    float* cd = colF;
    float* ci = rowF;
#pragma unroll
    for (int i = 0; i < 2; ++i) {
        const int r = rl + 16 * i;
#pragma unroll
        for (int k = 0; k < 6; ++k) {
            cd[(r * 16 + cl) * 6 + k] = bd[i][k];
            ci[(r * 16 + cl) * 6 + k] = __int_as_float(bi[i][k]);
        }
    }
    __syncthreads();
    if (tid < RB) {
        float md[6]; int mi[6];
#pragma unroll
        for (int k = 0; k < 6; ++k) { md[k] = 3.0e38f; mi[k] = 0; }
        for (int g = 0; g < 16; ++g) {
#pragma unroll
            for (int k = 0; k < 6; ++k)
                insert6(cd[(tid * 16 + g) * 6 + k],
                        __float_as_int(ci[(tid * 16 + g) * 6 + k]), md, mi);
        }
        float* dst = &out[(size_t)(row0 + tid) * NPTS + cs * 12];
#pragma unroll
        for (int k = 0; k < 6; ++k) {
            dst[k] = md[k];
            dst[6 + k] = __int_as_float(mi[k]);
        }
    }
}

__global__ __launch_bounds__(256) void knn_finalize(float* __restrict__ out) {
    __shared__ float pbuf[SPLITS * 12];
    __shared__ float w_s[6];
    __shared__ int   wi_s[6];

    const int    tid  = threadIdx.x;
    const size_t base = (size_t)blockIdx.x * NPTS;

    if (tid < SPLITS * 12) pbuf[tid] = out[base + tid];
    __syncthreads();

    if (tid == 0) {
        float md[6]; int mi[6];
#pragma unroll
        for (int k = 0; k < 6; ++k) { md[k] = 3.0e38f; mi[k] = 0; }
        for (int s = 0; s < SPLITS; ++s)
#pragma unroll
            for (int k = 0; k < 6; ++k)
                insert6(pbuf[s * 12 + k], __float_as_int(pbuf[s * 12 + 6 + k]), md, mi);
        const float T = sqrtf(md[5]);
        float w[6]; float norm = 0.f;
#pragma unroll
        for (int k = 0; k < 6; ++k) { w[k] = T - sqrtf(md[k]) + 1e-10f; norm += w[k]; }
        const float inv = 1.0f / fmaxf(norm, 1e-12f);
#pragma unroll
        for (int k = 0; k < 6; ++k) { w_s[k] = w[k] * inv; wi_s[k] = mi[k]; }
    }
    __syncthreads();

#pragma unroll
    for (int m = 0; m < 8; ++m)
        *(float4*)&out[base + (size_t)(m * 256 + tid) * 4] = make_float4(0.f, 0.f, 0.f, 0.f);
    __syncthreads();

    if (tid < 6) out[base + wi_s[tid]] = w_s[tid];
}

extern "C" void kernel_launch(void* const* d_in, const int* in_sizes, int n_in,
                              void* d_out, int out_size, void* d_ws, size_t ws_size,
                              hipStream_t stream) {
    const float* F   = (const float*)d_in[0];
    float*       out = (float*)d_out;
    if (ws_size >= WS_NEED) {
        short* H   = (short*)((char*)d_ws + WS_HI);
        float* sqp = (float*)((char*)d_ws + WS_SQ);
        float* prt = (float*)((char*)d_ws + WS_PART);
        prep3<<<dim3(NPTS * DIM / 512), dim3(256), 0, stream>>>(F, H, sqp);
        knn_mfma3<<<dim3(64 * NSPLIT), dim3(256), 0, stream>>>(H, sqp, prt, out);
        final3<<<dim3(NPTS / 256), dim3(256), 0, stream>>>(prt, out);
    } else {
        knn_partial<<<dim3((NPTS / RB) * SPLITS), dim3(256), 0, stream>>>(F, out);
        knn_finalize<<<dim3(NPTS), dim3(256), 0, stream>>>(out);
    }
}

// Round 4
// 278.244 us; speedup vs baseline: 1.0691x; 1.0087x over previous
//
#include <hip/hip_runtime.h>
#include <cstddef>
#include <cstdint>

#define NPTS 8192
#define DIM  128

// MFMA path (round-15): single-plane f16 GEMM, K3=128, A staged ONCE,
// counted-vmcnt barriers (T4): the per-step barrier waits ONLY for the
// previous step's 4 global_load_lds (vmcnt(8) leaves the 8 newest VMEM ops
// -- the zero-fill stores -- in flight), instead of the compiler's full
// vmcnt(0) drain. Post-mortem r2/r3: NT stores (slower acks) hurt and
// A-once (fewer loads) was neutral -> store-ack drain at each barrier is
// the critical path; fill stores don't need to be waited on at barriers
// at all (kernel-end release handles visibility for final3).
// LDS: A 2x16KB K-sections | B double-buffer 2x16KB = 64KB (merge dump reuses).
#define K3      128
#define BK      64
#define KITERS  (K3 / BK)        // 2
#define BM      128
#define BN      128
#define NSPLIT  8
#define CPB2    (NPTS / NSPLIT)  // 1024
#define NT2     (CPB2 / BN)      // 8

using f16x8 = __attribute__((ext_vector_type(8))) _Float16;
using f32x4 = __attribute__((ext_vector_type(4))) float;

// ws layout (bytes): H (f16 plane) | sq | part (8192 rows x 8 splits x 6 keys)
#define WS_HI   ((size_t)0)
#define WS_SQ   ((size_t)NPTS * DIM * 2)            // 2 MB
#define WS_PART (WS_SQ + (size_t)NPTS * 4)          // +32 KB
#define WS_NEED (WS_PART + (size_t)NPTS * 48 * 4)   // ~3.6 MB

// branchless sorted-ascending insert of packed key (positive floats only)
__device__ __forceinline__ void ins6(float t, float bd[6]) {
#pragma unroll
    for (int q = 0; q < 6; ++q) {
        float lo = fminf(bd[q], t);
        t        = fmaxf(bd[q], t);
        bd[q]    = lo;
    }
}

// classic (d2, idx) insert for the small final merge
__device__ __forceinline__ void insert6(float d, int idx, float bd[6], int bi[6]) {
    if (d < bd[5]) {
        bd[5] = d; bi[5] = idx;
#pragma unroll
        for (int q = 5; q >= 1; --q) {
            if (bd[q] < bd[q - 1]) {
                float td = bd[q]; bd[q] = bd[q - 1]; bd[q - 1] = td;
                int   ti = bi[q]; bi[q] = bi[q - 1]; bi[q - 1] = ti;
            }
        }
    }
}

__device__ __forceinline__ void async16(const void* g, void* l) {
    __builtin_amdgcn_global_load_lds(
        (const __attribute__((address_space(1))) void*)g,
        (__attribute__((address_space(3))) void*)l,
        16, 0, 0);
}

// K0: fp32 -> f16 plane (RNE via v_cvt_f16_f32) + per-row |f16|^2 via shfl.
// 2 elems/thread: one wave == one 128-dim row, so no LDS reduction needed.
__global__ __launch_bounds__(256) void prep3(const float* __restrict__ F,
                                             short* __restrict__ H,
                                             float* __restrict__ sq) {
    const int tid = threadIdx.x;
    const int idx = blockIdx.x * 512 + tid * 2;
    float2 f = *(const float2*)&F[idx];
    _Float16 h0 = (_Float16)f.x;          // RNE
    _Float16 h1 = (_Float16)f.y;
    ushort2 hp;
    hp.x = __builtin_bit_cast(unsigned short, h0);
    hp.y = __builtin_bit_cast(unsigned short, h1);
    *(ushort2*)&H[idx] = hp;
    const float a = (float)h0, b = (float)h1;
    float s = a * a + b * b;              // sq of the QUANTIZED point
#pragma unroll
    for (int m = 32; m >= 1; m >>= 1) s += __shfl_xor(s, m, 64);
    if ((tid & 63) == 0) sq[blockIdx.x * 4 + (tid >> 6)] = s;
}

// K1: swapped-operand f16 MFMA distance + packed-key top-6 + interleaved
// zero-fill of the output strip. A staged once; B double-buffered;
// counted-vmcnt barriers keep fill stores in flight across steps.
__global__ __launch_bounds__(256, 2) void knn_mfma3(const short* __restrict__ H,
                                                    const float* __restrict__ sq,
                                                    float* __restrict__ part,
                                                    float* __restrict__ out) {
    __shared__ __align__(16) char smraw[65536];   // [A 32KB][B dbuf 2x16KB]; dump reuses 24KB
    char* const smA = smraw;
    char* const smB = smraw + 32768;

    const int tid  = threadIdx.x;
    const int lane = tid & 63;
    const int w    = tid >> 6;        // wave 0..3
    const int wy   = w >> 1;          // col half
    const int wx   = w & 1;           // row half
    const int q    = lane >> 4;       // quad 0..3
    const int pl   = lane & 15;

    const int bx   = blockIdx.x;
    const int rb   = bx & 63;
    const int cs   = bx >> 6;
    const int row0 = rb * BM;
    const int col0 = cs * CPB2;

    // B staging decode: slot = w*256 + i*64 + lane -> (point, logical chunk)
    int pS[4], cS[4];
#pragma unroll
    for (int i = 0; i < 4; ++i) {
        int ch = w * 256 + i * 64 + lane;
        pS[i] = ch >> 3;
        cS[i] = (ch & 7) ^ (pS[i] & 7);
    }

    // frag LDS byte offsets: phys chunk = point*8 + (kchunk ^ (point&7))
    int colOff[4][2], rowOff[4][2];
#pragma unroll
    for (int f = 0; f < 4; ++f) {
#pragma unroll
        for (int s = 0; s < 2; ++s) {
            int pc = wy * 64 + f * 16 + pl;
            int cc = (s * 4 + q) ^ (pc & 7);
            colOff[f][s] = (pc * 64 + cc * 8) * 2;
            int pr = wx * 64 + f * 16 + pl;
            int cr = (s * 4 + q) ^ (pr & 7);
            rowOff[f][s] = (pr * 64 + cr * 8) * 2;
        }
    }

    float sqr4[4];
#pragma unroll
    for (int fj = 0; fj < 4; ++fj) sqr4[fj] = sq[row0 + wx * 64 + fj * 16 + pl];

    // packed-key top-6 per owned row (4 rows per thread)
    float bd[4][6];
#pragma unroll
    for (int fj = 0; fj < 4; ++fj)
#pragma unroll
        for (int k = 0; k < 6; ++k) bd[fj][k] = 3.0e38f;

    // ---- stage A once: 2048 chunks (2 K-sections x 128 rows x 8 chunks).
    // dest slot = i*256 + tid (wave-uniform base + lane*16); source address
    // carries the swizzle: slot -> (s16, p, phys), logical chunk = phys^(p&7).
#pragma unroll
    for (int i = 0; i < 8; ++i) {
        int slot = i * 256 + tid;
        int s16  = slot >> 10;
        int wi   = slot & 1023;
        int p    = wi >> 3;
        int phys = wi & 7;
        int c8   = phys ^ (p & 7);
        const short* gA = H + (size_t)(row0 + p) * DIM + s16 * 64 + c8 * 8;
        async16(gA, smA + slot * 16);
    }

    auto stageB = [&](int b, int nt, int nk) {
        const int half = nk * 64;                  // K-section within the row
        const int tcn  = col0 + nt * BN;
        char* baseB = smB + b * 16384;
#pragma unroll
        for (int i = 0; i < 4; ++i) {
            const short* gB = H + (size_t)(tcn + pS[i]) * DIM + half + cS[i] * 8;
            async16(gB, baseB + (w * 256 + i * 64) * 16);
        }
    };

    stageB(0, 0, 0);
    int sidx = 0;

    const f32x4 z4 = {0.f, 0.f, 0.f, 0.f};

    for (int tile = 0; tile < NT2; ++tile) {
        const int tc0 = col0 + tile * BN;

        f32x4 acc[4][4];
#pragma unroll
        for (int fi = 0; fi < 4; ++fi)
#pragma unroll
            for (int fj = 0; fj < 4; ++fj) acc[fi][fj] = 0.0f;

        for (int kk = 0; kk < KITERS; ++kk) {
            const int b = sidx & 1;
            // Counted-vmcnt barrier: retire everything older than the 8
            // newest VMEM ops. Issue order per step = [4 stageB loads,
            // 8 fill stores], so vmcnt(8) always covers the loads that
            // filled the buffer we're about to read, while the fill
            // stores keep draining across the barrier. First step needs
            // the full prologue (8 A-loads + 4 B-loads) -> vmcnt(0).
            if (sidx == 0)
                asm volatile("s_waitcnt vmcnt(0) lgkmcnt(0)" ::: "memory");
            else
                asm volatile("s_waitcnt vmcnt(8) lgkmcnt(0)" ::: "memory");
            __builtin_amdgcn_s_barrier();

            int nk = kk + 1, nt = tile;
            if (nk == KITERS) { nk = 0; nt = tile + 1; }
            if (nt < NT2) stageB(b ^ 1, nt, nk);

            // interleaved zero-fill quota: 8 f32x4/thread/step (stores stay
            // in flight across barriers; visibility for final3 comes from
            // the kernel-end release). 16 steps x 2048 f32x4 = 32768 =
            // the full 128x1024 region.
            {
                int base = sidx * 2048 + tid;
#pragma unroll
                for (int it = 0; it < 8; ++it) {
                    int flat = base + it * 256;
                    int r  = flat >> 8;           // 0..127
                    int c4 = (flat & 255) * 4;    // 0..1020
                    *(f32x4*)&out[(size_t)(row0 + r) * NPTS + col0 + c4] = z4;
                }
            }

            char* baseB = smB + b * 16384;
            const char* baseA = smA + (kk << 14);  // K-section kk
#pragma unroll
            for (int s = 0; s < 2; ++s) {
                f16x8 cf[4], rf[4];
#pragma unroll
                for (int fi = 0; fi < 4; ++fi)
                    cf[fi] = *(const f16x8*)(baseB + colOff[fi][s]);
#pragma unroll
                for (int fj = 0; fj < 4; ++fj)
                    rf[fj] = *(const f16x8*)(baseA + rowOff[fj][s]);
#pragma unroll
                for (int fi = 0; fi < 4; ++fi)
#pragma unroll
                    for (int fj = 0; fj < 4; ++fj)
                        acc[fi][fj] = __builtin_amdgcn_mfma_f32_16x16x32_f16(
                            cf[fi], rf[fj], acc[fi][fj], 0, 0, 0);
            }
            ++sidx;
        }

        // in-register epilogue: rows r = wx*64+fj*16+pl, cols c = wy*64+fi*16+q*4+reg
        const bool diag = (tc0 == row0);
        float4 sqc4[4];
#pragma unroll
        for (int fi = 0; fi < 4; ++fi)
            sqc4[fi] = *(const float4*)&sq[tc0 + wy * 64 + fi * 16 + q * 4];

#pragma unroll
        for (int fj = 0; fj < 4; ++fj) {
            const float sr = sqr4[fj];
            const int   r  = wx * 64 + fj * 16 + pl;
#pragma unroll
            for (int fi = 0; fi < 4; ++fi) {
                const float* sc = (const float*)&sqc4[fi];
#pragma unroll
                for (int reg = 0; reg < 4; ++reg) {
                    const int c = wy * 64 + fi * 16 + q * 4 + reg;
                    float d2 = fmaf(-2.0f, acc[fi][fj][reg], sr + sc[reg]);
                    d2 = fmaxf(d2, 1e-30f);
                    if (diag && r == c) d2 = 1e-30f;    // self-distance
                    uint32_t kb = (__float_as_uint(d2) & 0xFFFFFC00u)
                                  | (uint32_t)(tile * BN + c);   // 10-bit local col
                    ins6(__uint_as_float(kb), bd[fj]);
                }
            }
        }
    }

    // block merge: 8 lists per row (wy x q) -> 6 packed keys per row per split
    __syncthreads();                       // full drain (once); reuse smraw
    float* dump = (float*)smraw;           // 128 rows * 8 copies * 6 = 24 KB
#pragma unroll
    for (int fj = 0; fj < 4; ++fj) {
        const int r    = wx * 64 + fj * 16 + pl;
        const int copy = wy * 4 + q;
        float* d = &dump[(size_t)(r * 8 + copy) * 6];
#pragma unroll
        for (int k = 0; k < 6; ++k) d[k] = bd[fj][k];
    }
    __syncthreads();
    if (tid < 128) {
        float md[6];
#pragma unroll
        for (int k = 0; k < 6; ++k) md[k] = 3.0e38f;
        const float* src = &dump[(size_t)tid * 48];
#pragma unroll
        for (int g = 0; g < 48; ++g) ins6(src[g], md);
        float* dst = part + (size_t)(row0 + tid) * 48 + cs * 6;
#pragma unroll
        for (int k = 0; k < 6; ++k) dst[k] = md[k];
    }
}

// K2: merge 8 packed-key lists per row (direct global reads, no LDS),
// compute weights, scatter 6 values.
__global__ __launch_bounds__(256) void final3(const float* __restrict__ part,
                                              float* __restrict__ out) {
    const int r = blockIdx.x * 256 + threadIdx.x;
    const float4* p4 = (const float4*)(part + (size_t)r * 48);
    float4 buf[12];
#pragma unroll
    for (int i = 0; i < 12; ++i) buf[i] = p4[i];
    const float* keys = (const float*)buf;

    float md[6]; int mi[6];
#pragma unroll
    for (int k = 0; k < 6; ++k) { md[k] = 3.0e38f; mi[k] = 0; }
#pragma unroll
    for (int s = 0; s < 8; ++s)
#pragma unroll
        for (int k = 0; k < 6; ++k) {
            uint32_t kb = __float_as_uint(keys[s * 6 + k]);
            float d2 = __uint_as_float(kb & 0xFFFFFC00u);
            int  col = s * CPB2 + (int)(kb & 1023u);
            insert6(d2, col, md, mi);
        }
    const float T = sqrtf(md[5]);
    float wv[6], norm = 0.f;
#pragma unroll
    for (int k = 0; k < 6; ++k) { wv[k] = T - sqrtf(md[k]) + 1e-10f; norm += wv[k]; }
    const float inv = 1.0f / fmaxf(norm, 1e-12f);
    const size_t base = (size_t)r * NPTS;
#pragma unroll
    for (int k = 0; k < 6; ++k) out[base + mi[k]] = wv[k] * inv;
}

// ------------------- fallback fp32 path (round 1, passing) -------------------
#define RB      32
#define CT      64
#define SPLITS  8
#define CPB     (NPTS / SPLITS)
#define NTILES  (CPB / CT)
#define PADS    132

__global__ __launch_bounds__(256) void knn_partial(const float* __restrict__ F,
                                                   float* __restrict__ out) {
    __shared__ float rowF[RB * PADS];
    __shared__ float colF[CT * PADS];
    __shared__ float sqr[RB];
    __shared__ float sqc[CT];

    const int tid  = threadIdx.x;
    const int bx   = blockIdx.x;
    const int rb   = bx & ((NPTS / RB) - 1);
    const int cs   = bx >> 8;
    const int row0 = rb * RB;
    const int col0 = cs * CPB;

#pragma unroll
    for (int m = 0; m < 4; ++m) {
        int flat = m * 256 + tid;
        int r = flat >> 5, kq = flat & 31;
        float4 v = *(const float4*)&F[(size_t)(row0 + r) * DIM + kq * 4];
        *(float4*)&rowF[r * PADS + kq * 4] = v;
    }
    __syncthreads();
    if (tid < RB) {
        float s = 0.f;
#pragma unroll
        for (int kq = 0; kq < 32; ++kq) {
            float4 v = *(const float4*)&rowF[tid * PADS + kq * 4];
            s += v.x * v.x + v.y * v.y + v.z * v.z + v.w * v.w;
        }
        sqr[tid] = s;
    }

    const int rl = tid >> 4;
    const int cl = tid & 15;

    float bd[2][6];
    int   bi[2][6];
#pragma unroll
    for (int i = 0; i < 2; ++i)
#pragma unroll
        for (int k = 0; k < 6; ++k) { bd[i][k] = 3.0e38f; bi[i][k] = 0; }

    for (int t = 0; t < NTILES; ++t) {
        const int cbase = col0 + t * CT;
        __syncthreads();
#pragma unroll
        for (int m = 0; m < 8; ++m) {
            int flat = m * 256 + tid;
            int c = flat >> 5, kq = flat & 31;
            float4 v = *(const float4*)&F[(size_t)(cbase + c) * DIM + kq * 4];
            *(float4*)&colF[c * PADS + kq * 4] = v;
        }
        __syncthreads();
        if (tid < CT) {
            float s = 0.f;
#pragma unroll
            for (int kq = 0; kq < 32; ++kq) {
                float4 v = *(const float4*)&colF[tid * PADS + kq * 4];
                s += v.x * v.x + v.y * v.y + v.z * v.z + v.w * v.w;
            }
            sqc[tid] = s;
        }
        __syncthreads();

        float acc[2][4];
#pragma unroll
        for (int i = 0; i < 2; ++i)
#pragma unroll
            for (int j = 0; j < 4; ++j) acc[i][j] = 0.f;

#pragma unroll 4
        for (int kq = 0; kq < 32; ++kq) {
            float4 a[2], b[4];
#pragma unroll
            for (int i = 0; i < 2; ++i)
                a[i] = *(const float4*)&rowF[(rl + 16 * i) * PADS + kq * 4];
#pragma unroll
            for (int j = 0; j < 4; ++j)
                b[j] = *(const float4*)&colF[(cl + 16 * j) * PADS + kq * 4];
#pragma unroll
            for (int i = 0; i < 2; ++i)
#pragma unroll
                for (int j = 0; j < 4; ++j) {
                    acc[i][j] = fmaf(a[i].x, b[j].x, acc[i][j]);
                    acc[i][j] = fmaf(a[i].y, b[j].y, acc[i][j]);
                    acc[i][j] = fmaf(a[i].z, b[j].z, acc[i][j]);
                    acc[i][j] = fmaf(a[i].w, b[j].w, acc[i][j]);
                }
        }

#pragma unroll
        for (int i = 0; i < 2; ++i) {
            const int r = rl + 16 * i;
            const int gr = row0 + r;
#pragma unroll
            for (int j = 0; j < 4; ++j) {
                const int c = cl + 16 * j;
                const int gc = cbase + c;
                float d2 = sqr[r] + sqc[c] - 2.0f * acc[i][j];
                d2 = (gr == gc) ? 1e-30f : fmaxf(d2, 1e-30f);
                insert6(d2, gc, bd[i], bi[i]);
            }
        }
    }

    __syncthreads();
    float* cd = colF;
    float* ci = rowF;
#pragma unroll
    for (int i = 0; i < 2; ++i) {
        const int r = rl + 16 * i;
#pragma unroll
        for (int k = 0; k < 6; ++k) {
            cd[(r * 16 + cl) * 6 + k] = bd[i][k];
            ci[(r * 16 + cl) * 6 + k] = __int_as_float(bi[i][k]);
        }
    }
    __syncthreads();
    if (tid < RB) {
        float md[6]; int mi[6];
#pragma unroll
        for (int k = 0; k < 6; ++k) { md[k] = 3.0e38f; mi[k] = 0; }
        for (int g = 0; g < 16; ++g) {
#pragma unroll
            for (int k = 0; k < 6; ++k)
                insert6(cd[(tid * 16 + g) * 6 + k],
                        __float_as_int(ci[(tid * 16 + g) * 6 + k]), md, mi);
        }
        float* dst = &out[(size_t)(row0 + tid) * NPTS + cs * 12];
#pragma unroll
        for (int k = 0; k < 6; ++k) {
            dst[k] = md[k];
            dst[6 + k] = __int_as_float(mi[k]);
        }
    }
}

__global__ __launch_bounds__(256) void knn_finalize(float* __restrict__ out) {
    __shared__ float pbuf[SPLITS * 12];
    __shared__ float w_s[6];
    __shared__ int   wi_s[6];

    const int    tid  = threadIdx.x;
    const size_t base = (size_t)blockIdx.x * NPTS;

    if (tid < SPLITS * 12) pbuf[tid] = out[base + tid];
    __syncthreads();

    if (tid == 0) {
        float md[6]; int mi[6];
#pragma unroll
        for (int k = 0; k < 6; ++k) { md[k] = 3.0e38f; mi[k] = 0; }
        for (int s = 0; s < SPLITS; ++s)
#pragma unroll
            for (int k = 0; k < 6; ++k)
                insert6(pbuf[s * 12 + k], __float_as_int(pbuf[s * 12 + 6 + k]), md, mi);
        const float T = sqrtf(md[5]);
        float w[6]; float norm = 0.f;
#pragma unroll
        for (int k = 0; k < 6; ++k) { w[k] = T - sqrtf(md[k]) + 1e-10f; norm += w[k]; }
        const float inv = 1.0f / fmaxf(norm, 1e-12f);
#pragma unroll
        for (int k = 0; k < 6; ++k) { w_s[k] = w[k] * inv; wi_s[k] = mi[k]; }
    }
    __syncthreads();

#pragma unroll
    for (int m = 0; m < 8; ++m)
        *(float4*)&out[base + (size_t)(m * 256 + tid) * 4] = make_float4(0.f, 0.f, 0.f, 0.f);
    __syncthreads();

    if (tid < 6) out[base + wi_s[tid]] = w_s[tid];
}

extern "C" void kernel_launch(void* const* d_in, const int* in_sizes, int n_in,
                              void* d_out, int out_size, void* d_ws, size_t ws_size,
                              hipStream_t stream) {
    const float* F   = (const float*)d_in[0];
    float*       out = (float*)d_out;
    if (ws_size >= WS_NEED) {
        short* H   = (short*)((char*)d_ws + WS_HI);
        float* sqp = (float*)((char*)d_ws + WS_SQ);
        float* prt = (float*)((char*)d_ws + WS_PART);
        prep3<<<dim3(NPTS * DIM / 512), dim3(256), 0, stream>>>(F, H, sqp);
        knn_mfma3<<<dim3(64 * NSPLIT), dim3(256), 0, stream>>>(H, sqp, prt, out);
        final3<<<dim3(NPTS / 256), dim3(256), 0, stream>>>(prt, out);
    } else {
        knn_partial<<<dim3((NPTS / RB) * SPLITS), dim3(256), 0, stream>>>(F, out);
        knn_finalize<<<dim3(NPTS), dim3(256), 0, stream>>>(out);
    }
}